// Round 1
// baseline (555.212 us; speedup 1.0000x reference)
//
#include <hip/hip_runtime.h>

#define N_NODES 50000
#define N_EDGES 800000
#define EPS_BN 1e-5f

// ws layout (as 32-bit words):
//  [0..64)    sum_e      [64..128)  sumsq_e   [128..192) scale_e  [192..256) shift_e
//  [256..320) sum_n      [320..384) sumsq_n   [384..448) scale_n  [448..512) shift_n
//  [512..2075)  flag bits (50000 nodes -> 1563 words)
//  [2080..8224) W_upd as bf16 pairs (64x192 = 12288 bf16 = 6144 words)

typedef __attribute__((ext_vector_type(8))) short s16x8;
typedef __attribute__((ext_vector_type(4))) float f32x4;

__device__ __forceinline__ unsigned short f2bf(float f) {
  unsigned int u = __float_as_uint(f);
  u += 0x7FFFu + ((u >> 16) & 1u);   // round-to-nearest-even
  return (unsigned short)(u >> 16);
}
__device__ __forceinline__ unsigned int pack2(float lo, float hi) {
  return (unsigned int)f2bf(lo) | ((unsigned int)f2bf(hi) << 16);
}

// ---------------- K0: zero stats+flags, convert W_upd -> bf16 ----------------
__global__ void k_init(unsigned int* __restrict__ wsu, const float* __restrict__ W_upd) {
  int i = blockIdx.x * 256 + threadIdx.x;
  if (i < 2075) wsu[i] = 0u;
  int j = i - 2080;
  if (j >= 0 && j < 6144) {
    float2 w2 = *(const float2*)&W_upd[(size_t)j * 2];
    wsu[2080 + j] = pack2(w2.x, w2.y);
  }
}

// ---------------- edge kernels: PHASE 0 = stats(+flags), PHASE 1 = output ----
template<int PHASE>
__global__ __launch_bounds__(256, 2) void k_edge(
    const float* __restrict__ h, const float* __restrict__ e,
    const int* __restrict__ src, const int* __restrict__ dst,
    const short* __restrict__ Wub, const float* __restrict__ b_upd,
    float* __restrict__ ws, unsigned int* __restrict__ flags,
    float* __restrict__ out_e)
{
  __shared__ short Als[128 * 192];   // bf16 A tile, float4-granule XOR swizzled
  __shared__ float sBias[64];
  __shared__ float sScale[64];
  __shared__ float sShift[64];

  int tid = threadIdx.x;
  int ln = tid & 63, wv = tid >> 6;
  int m0 = blockIdx.x * 128;

  if (tid < 64) {
    sBias[tid] = b_upd[tid];
    if (PHASE == 1) { sScale[tid] = ws[128 + tid]; sShift[tid] = ws[192 + tid]; }
  }

  // ---- stage A tile: row = edge, cols [h[src] | h[dst] | e] as bf16 ----
  {
    unsigned int* A32 = (unsigned int*)Als;
    int c2 = ln & 31;                    // float2 column index within a 64-col segment
    int rb = wv * 32 + (ln >> 5);
    #pragma unroll
    for (int it = 0; it < 16; ++it) {
      int r = rb + it * 2;
      int m = m0 + r;
      int s = src[m];
      int d = dst[m];
      float2 vs = *(const float2*)&h[(size_t)s * 64 + c2 * 2];
      float2 vd = *(const float2*)&h[(size_t)d * 64 + c2 * 2];
      float2 ve = *(const float2*)&e[(size_t)m * 64 + c2 * 2];
      int xr = r & 7;
      int w = c2 & 3;
      A32[r * 96 + ((((c2      ) >> 2) ^ xr) << 2 | w)] = pack2(vs.x, vs.y);
      A32[r * 96 + ((((c2 + 32 ) >> 2) ^ xr) << 2 | w)] = pack2(vd.x, vd.y);
      A32[r * 96 + ((((c2 + 64 ) >> 2) ^ xr) << 2 | w)] = pack2(ve.x, ve.y);
      if (PHASE == 0 && (ln & 31) == 0)
        atomicOr(&flags[d >> 5], 1u << (d & 31));
    }
  }
  __syncthreads();

  // ---- MFMA: each wave does 32 rows x 64 cols, K = 192 ----
  int lr = ln & 15;
  int lk = (ln >> 4) * 8;
  f32x4 zero4 = {0.f, 0.f, 0.f, 0.f};
  f32x4 acc[2][4];
  #pragma unroll
  for (int rt = 0; rt < 2; ++rt)
    #pragma unroll
    for (int ct = 0; ct < 4; ++ct) acc[rt][ct] = zero4;

  int r0 = wv * 32 + lr;
  int r1 = r0 + 16;
  #pragma unroll
  for (int kk = 0; kk < 6; ++kk) {
    int k0 = kk * 32 + lk;
    s16x8 a0 = *(const s16x8*)&Als[r0 * 192 + (((k0 >> 3) ^ (r0 & 7)) << 3)];
    s16x8 a1 = *(const s16x8*)&Als[r1 * 192 + (((k0 >> 3) ^ (r1 & 7)) << 3)];
    #pragma unroll
    for (int ct = 0; ct < 4; ++ct) {
      s16x8 b = *(const s16x8*)&Wub[(ct * 16 + lr) * 192 + k0];
      acc[0][ct] = __builtin_amdgcn_mfma_f32_16x16x32_bf16(a0, b, acc[0][ct], 0, 0, 0);
      acc[1][ct] = __builtin_amdgcn_mfma_f32_16x16x32_bf16(a1, b, acc[1][ct], 0, 0, 0);
    }
  }

  if (PHASE == 0) {
    // per-feature sum / sumsq over this block's 128 edges
    float s1[4], s2[4];
    #pragma unroll
    for (int ct = 0; ct < 4; ++ct) {
      float bias = sBias[ct * 16 + lr];
      float a1s = 0.f, a2s = 0.f;
      #pragma unroll
      for (int rt = 0; rt < 2; ++rt)
        #pragma unroll
        for (int q = 0; q < 4; ++q) {
          float v = acc[rt][ct][q] + bias;
          a1s += v; a2s += v * v;
        }
      s1[ct] = a1s; s2[ct] = a2s;
    }
    #pragma unroll
    for (int ct = 0; ct < 4; ++ct) {
      s1[ct] += __shfl_xor(s1[ct], 16); s1[ct] += __shfl_xor(s1[ct], 32);
      s2[ct] += __shfl_xor(s2[ct], 16); s2[ct] += __shfl_xor(s2[ct], 32);
    }
    // wave-private scratch inside own A rows (no barrier needed before write)
    float* red1 = (float*)&Als[(wv * 32) * 192];
    float* red2 = (float*)&Als[(wv * 32 + 1) * 192];
    if (ln < 16) {
      #pragma unroll
      for (int ct = 0; ct < 4; ++ct) { red1[ct * 16 + ln] = s1[ct]; red2[ct * 16 + ln] = s2[ct]; }
    }
    __syncthreads();
    if (tid < 64) {
      float t1 = 0.f, t2 = 0.f;
      #pragma unroll
      for (int w = 0; w < 4; ++w) {
        t1 += ((const float*)&Als[(w * 32) * 192])[tid];
        t2 += ((const float*)&Als[(w * 32 + 1) * 192])[tid];
      }
      atomicAdd(&ws[tid], t1);
      atomicAdd(&ws[64 + tid], t2);
    }
  } else {
    // e2 = e + silu(bn(e_lin))
    #pragma unroll
    for (int rt = 0; rt < 2; ++rt)
      #pragma unroll
      for (int ct = 0; ct < 4; ++ct) {
        int col = ct * 16 + lr;
        float scale = sScale[col], shift = sShift[col], bias = sBias[col];
        #pragma unroll
        for (int q = 0; q < 4; ++q) {
          int row = wv * 32 + rt * 16 + (ln >> 4) * 4 + q;
          size_t idx = (size_t)(m0 + row) * 64 + col;
          float x = acc[rt][ct][q] + bias;
          float bnv = x * scale + shift;
          float sl = bnv / (1.f + __expf(-bnv));
          out_e[idx] = e[idx] + sl;
        }
      }
  }
}

// ---------------- finalize BN stats -> scale/shift ----------------
__global__ void k_fin(float* __restrict__ ws, const float* __restrict__ gamma,
                      const float* __restrict__ beta, float rcount, int off) {
  int d = threadIdx.x;
  float mean = ws[off + d] * rcount;
  float var = ws[off + 64 + d] * rcount - mean * mean;
  float inv = rsqrtf(var + EPS_BN);
  float a = inv * gamma[d];
  ws[off + 128 + d] = a;
  ws[off + 192 + d] = beta[d] - mean * a;
}

// ---------------- node stats: h2p = hgs + flag*hgd, accumulate sum/sumsq ----
__global__ __launch_bounds__(256, 2) void k_node_stats(
    const float* __restrict__ h,
    const float* __restrict__ W_gd, const float* __restrict__ b_gd,
    const float* __restrict__ W_gs, const float* __restrict__ b_gs,
    float* __restrict__ ws, const unsigned int* __restrict__ flags)
{
  __shared__ float Hs[64 * 64];
  __shared__ float Wd[64 * 64];
  __shared__ float Wg[64 * 64];
  __shared__ float red[2][256];
  int tid = threadIdx.x;
  int n0 = blockIdx.x * 64;
  for (int i = tid; i < 1024; i += 256) {
    int r = i >> 4, k4 = i & 15;
    int sw = (k4 ^ (r & 15)) << 2;
    *(float4*)&Wd[r * 64 + sw] = *(const float4*)&W_gd[(size_t)r * 64 + k4 * 4];
    *(float4*)&Wg[r * 64 + sw] = *(const float4*)&W_gs[(size_t)r * 64 + k4 * 4];
    int n = n0 + r;
    float4 hv = {0.f, 0.f, 0.f, 0.f};
    if (n < N_NODES) hv = *(const float4*)&h[(size_t)n * 64 + k4 * 4];
    *(float4*)&Hs[r * 64 + k4 * 4] = hv;
  }
  __syncthreads();
  int d = tid & 63, g = tid >> 6;
  float bd = b_gd[d], bs = b_gs[d];
  float s1 = 0.f, s2 = 0.f;
  #pragma unroll
  for (int i = 0; i < 16; ++i) {
    int nl = g + 4 * i;
    int n = n0 + nl;
    if (n < N_NODES) {
      float accd = 0.f, accs = 0.f;
      #pragma unroll
      for (int k4 = 0; k4 < 16; ++k4) {
        float4 hv = *(const float4*)&Hs[nl * 64 + k4 * 4];
        float4 w1 = *(const float4*)&Wd[d * 64 + ((k4 ^ (d & 15)) << 2)];
        float4 w2 = *(const float4*)&Wg[d * 64 + ((k4 ^ (d & 15)) << 2)];
        accd += hv.x * w1.x + hv.y * w1.y + hv.z * w1.z + hv.w * w1.w;
        accs += hv.x * w2.x + hv.y * w2.y + hv.z * w2.z + hv.w * w2.w;
      }
      unsigned int fl = (flags[n >> 5] >> (n & 31)) & 1u;
      float v = accs + bs + (fl ? (accd + bd) : 0.f);
      s1 += v; s2 += v * v;
    }
  }
  red[0][tid] = s1; red[1][tid] = s2;
  __syncthreads();
  if (tid < 64) {
    float t1 = red[0][tid] + red[0][tid + 64] + red[0][tid + 128] + red[0][tid + 192];
    float t2 = red[1][tid] + red[1][tid + 64] + red[1][tid + 128] + red[1][tid + 192];
    atomicAdd(&ws[256 + tid], t1);
    atomicAdd(&ws[320 + tid], t2);
  }
}

// ---------------- node output: h2 = (silu(bn(h2p)) + h) @ W_out.T + b_out ----
__global__ __launch_bounds__(256, 2) void k_node_out(
    const float* __restrict__ h,
    const float* __restrict__ W_gd, const float* __restrict__ b_gd,
    const float* __restrict__ W_gs, const float* __restrict__ b_gs,
    const float* __restrict__ W_out, const float* __restrict__ b_out,
    const float* __restrict__ ws, const unsigned int* __restrict__ flags,
    float* __restrict__ out_h)
{
  __shared__ float Hs[64 * 64];
  __shared__ float W1[64 * 64];
  __shared__ float W2[64 * 64];
  int tid = threadIdx.x;
  int n0 = blockIdx.x * 64;
  for (int i = tid; i < 1024; i += 256) {
    int r = i >> 4, k4 = i & 15;
    int sw = (k4 ^ (r & 15)) << 2;
    *(float4*)&W1[r * 64 + sw] = *(const float4*)&W_gd[(size_t)r * 64 + k4 * 4];
    *(float4*)&W2[r * 64 + sw] = *(const float4*)&W_gs[(size_t)r * 64 + k4 * 4];
    int n = n0 + r;
    float4 hv = {0.f, 0.f, 0.f, 0.f};
    if (n < N_NODES) hv = *(const float4*)&h[(size_t)n * 64 + k4 * 4];
    *(float4*)&Hs[r * 64 + k4 * 4] = hv;
  }
  __syncthreads();
  int d = tid & 63, g = tid >> 6;
  float a_n = ws[384 + d], b_n = ws[448 + d];
  float bd = b_gd[d], bs = b_gs[d];
  float tv[16];
  #pragma unroll
  for (int i = 0; i < 16; ++i) {
    int nl = g + 4 * i;
    int n = n0 + nl;
    if (n < N_NODES) {
      float accd = 0.f, accs = 0.f;
      #pragma unroll
      for (int k4 = 0; k4 < 16; ++k4) {
        float4 hv = *(const float4*)&Hs[nl * 64 + k4 * 4];
        float4 w1 = *(const float4*)&W1[d * 64 + ((k4 ^ (d & 15)) << 2)];
        float4 w2 = *(const float4*)&W2[d * 64 + ((k4 ^ (d & 15)) << 2)];
        accd += hv.x * w1.x + hv.y * w1.y + hv.z * w1.z + hv.w * w1.w;
        accs += hv.x * w2.x + hv.y * w2.y + hv.z * w2.z + hv.w * w2.w;
      }
      unsigned int fl = (flags[n >> 5] >> (n & 31)) & 1u;
      float v = accs + bs + (fl ? (accd + bd) : 0.f);
      float bnv = v * a_n + b_n;
      float sl = bnv / (1.f + __expf(-bnv));
      tv[i] = sl + Hs[nl * 64 + d];
    }
  }
  __syncthreads();   // all Hs/W1 reads complete
  for (int i = tid; i < 1024; i += 256) {
    int r = i >> 4, k4 = i & 15;
    *(float4*)&W1[r * 64 + ((k4 ^ (r & 15)) << 2)] = *(const float4*)&W_out[(size_t)r * 64 + k4 * 4];
  }
  #pragma unroll
  for (int i = 0; i < 16; ++i) {
    int nl = g + 4 * i;
    int n = n0 + nl;
    if (n < N_NODES) Hs[nl * 64 + d] = tv[i];
  }
  __syncthreads();
  float bo = b_out[d];
  #pragma unroll
  for (int i = 0; i < 16; ++i) {
    int nl = g + 4 * i;
    int n = n0 + nl;
    if (n < N_NODES) {
      float acc = 0.f;
      #pragma unroll
      for (int k4 = 0; k4 < 16; ++k4) {
        float4 t4 = *(const float4*)&Hs[nl * 64 + k4 * 4];
        float4 w4 = *(const float4*)&W1[d * 64 + ((k4 ^ (d & 15)) << 2)];
        acc += t4.x * w4.x + t4.y * w4.y + t4.z * w4.z + t4.w * w4.w;
      }
      out_h[(size_t)n * 64 + d] = acc + bo;
    }
  }
}

extern "C" void kernel_launch(void* const* d_in, const int* in_sizes, int n_in,
                              void* d_out, int out_size, void* d_ws, size_t ws_size,
                              hipStream_t stream) {
  const float* h     = (const float*)d_in[0];
  const float* e     = (const float*)d_in[1];
  const int*   src   = (const int*)d_in[2];
  const int*   dst   = (const int*)d_in[3];
  const float* W_upd = (const float*)d_in[4];
  const float* b_upd = (const float*)d_in[5];
  const float* g_un  = (const float*)d_in[6];
  const float* be_un = (const float*)d_in[7];
  // d_in[8], d_in[9]: W_act, b_act -- dead (softmax weights sum to 1 per dst)
  const float* W_gd  = (const float*)d_in[10];
  const float* b_gd  = (const float*)d_in[11];
  const float* W_gs  = (const float*)d_in[12];
  const float* b_gs  = (const float*)d_in[13];
  const float* g_gn  = (const float*)d_in[14];
  const float* be_gn = (const float*)d_in[15];
  const float* W_out = (const float*)d_in[16];
  const float* b_out = (const float*)d_in[17];

  float* outH = (float*)d_out;
  float* outE = outH + (size_t)N_NODES * 64;
  float* ws = (float*)d_ws;
  unsigned int* wsu = (unsigned int*)d_ws;
  unsigned int* flags = wsu + 512;
  const short* Wub = (const short*)(wsu + 2080);

  k_init<<<33, 256, 0, stream>>>(wsu, W_upd);
  k_edge<0><<<N_EDGES / 128, 256, 0, stream>>>(h, e, src, dst, Wub, b_upd, ws, flags, nullptr);
  k_fin<<<1, 64, 0, stream>>>(ws, g_un, be_un, 1.f / (float)N_EDGES, 0);
  k_edge<1><<<N_EDGES / 128, 256, 0, stream>>>(h, e, src, dst, Wub, b_upd, ws, flags, outE);
  k_node_stats<<<(N_NODES + 63) / 64, 256, 0, stream>>>(h, W_gd, b_gd, W_gs, b_gs, ws, flags);
  k_fin<<<1, 64, 0, stream>>>(ws, g_gn, be_gn, 1.f / (float)N_NODES, 256);
  k_node_out<<<(N_NODES + 63) / 64, 256, 0, stream>>>(h, W_gd, b_gd, W_gs, b_gs, W_out, b_out, ws, flags, outH);
}

// Round 2
// 521.104 us; speedup vs baseline: 1.0655x; 1.0655x over previous
//
#include <hip/hip_runtime.h>

#define N_NODES 50000
#define N_EDGES 800000
#define EPS_BN 1e-5f

// ws layout (as 32-bit words):
//  [0..64)    sum_e      [64..128)  sumsq_e   [128..192) scale_e  [192..256) shift_e
//  [256..320) sum_n      [320..384) sumsq_n   [384..448) scale_n  [448..512) shift_n
//  [512..2075)  flag bits (50000 nodes -> 1563 words)
//  [2080..8224) W_upd as bf16 pairs (64x192 = 12288 bf16 = 6144 words)

typedef __attribute__((ext_vector_type(8))) short s16x8;
typedef __attribute__((ext_vector_type(4))) float f32x4;

__device__ __forceinline__ unsigned short f2bf(float f) {
  unsigned int u = __float_as_uint(f);
  u += 0x7FFFu + ((u >> 16) & 1u);   // round-to-nearest-even
  return (unsigned short)(u >> 16);
}
__device__ __forceinline__ unsigned int pack2(float lo, float hi) {
  return (unsigned int)f2bf(lo) | ((unsigned int)f2bf(hi) << 16);
}
__device__ __forceinline__ s16x8 cvt8(float4 a, float4 b) {
  union { s16x8 v; unsigned int u[4]; } r;
  r.u[0] = pack2(a.x, a.y);
  r.u[1] = pack2(a.z, a.w);
  r.u[2] = pack2(b.x, b.y);
  r.u[3] = pack2(b.z, b.w);
  return r.v;
}

// ---------------- K0: zero stats+flags, convert W_upd -> bf16 ----------------
__global__ void k_init(unsigned int* __restrict__ wsu, const float* __restrict__ W_upd) {
  int i = blockIdx.x * 256 + threadIdx.x;
  if (i < 2075) wsu[i] = 0u;
  int j = i - 2080;
  if (j >= 0 && j < 6144) {
    float2 w2 = *(const float2*)&W_upd[(size_t)j * 2];
    wsu[2080 + j] = pack2(w2.x, w2.y);
  }
}

// ---------------- edge kernels: PHASE 0 = stats(+flags), PHASE 1 = output ----
// No LDS A-tile: each wave's 32 rows are private (no cross-wave reuse existed),
// so A fragments go global->reg directly: 24 independent float4 loads/lane,
// deep MLP pipeline, no barrier in the load path. B (24KB) stays L1-resident.
template<int PHASE>
__global__ __launch_bounds__(256, 4) void k_edge(
    const float* __restrict__ h, const float* __restrict__ e,
    const int* __restrict__ src, const int* __restrict__ dst,
    const short* __restrict__ Wub, const float* __restrict__ b_upd,
    float* __restrict__ ws, unsigned int* __restrict__ flags,
    float* __restrict__ out_e)
{
  __shared__ float red[4][128];   // phase-0 cross-wave stats only (2 KB)

  int tid = threadIdx.x;
  int ln = tid & 63, wv = tid >> 6;
  int lr = ln & 15, lq = ln >> 4;
  int lk = lq * 8;
  int m0 = blockIdx.x * 128;
  int r0 = wv * 32 + lr;          // A-frag row for acc[0]
  int r1 = r0 + 16;               // A-frag row for acc[1]
  int mA = m0 + r0, mB = m0 + r1;

  int s0 = src[mA], d0 = dst[mA];
  int s1i = src[mB], d1 = dst[mB];

  if (PHASE == 0 && lq == 0) {
    atomicOr(&flags[d0 >> 5], 1u << (d0 & 31));
    atomicOr(&flags[d1 >> 5], 1u << (d1 & 31));
  }

  const float* pa0 = h + (size_t)s0 * 64 + lk;
  const float* pa1 = h + (size_t)d0 * 64 + lk;
  const float* pa2 = e + (size_t)mA * 64 + lk;
  const float* pb0 = h + (size_t)s1i * 64 + lk;
  const float* pb1 = h + (size_t)d1 * 64 + lk;
  const float* pb2 = e + (size_t)mB * 64 + lk;

  // K layout: kk 0,1 <- h[src]; kk 2,3 <- h[dst]; kk 4,5 <- e
  s16x8 A0[6], A1[6];
  A0[0] = cvt8(*(const float4*)(pa0),      *(const float4*)(pa0 + 4));
  A0[1] = cvt8(*(const float4*)(pa0 + 32), *(const float4*)(pa0 + 36));
  A0[2] = cvt8(*(const float4*)(pa1),      *(const float4*)(pa1 + 4));
  A0[3] = cvt8(*(const float4*)(pa1 + 32), *(const float4*)(pa1 + 36));
  A0[4] = cvt8(*(const float4*)(pa2),      *(const float4*)(pa2 + 4));
  A0[5] = cvt8(*(const float4*)(pa2 + 32), *(const float4*)(pa2 + 36));
  A1[0] = cvt8(*(const float4*)(pb0),      *(const float4*)(pb0 + 4));
  A1[1] = cvt8(*(const float4*)(pb0 + 32), *(const float4*)(pb0 + 36));
  A1[2] = cvt8(*(const float4*)(pb1),      *(const float4*)(pb1 + 4));
  A1[3] = cvt8(*(const float4*)(pb1 + 32), *(const float4*)(pb1 + 36));
  A1[4] = cvt8(*(const float4*)(pb2),      *(const float4*)(pb2 + 4));
  A1[5] = cvt8(*(const float4*)(pb2 + 32), *(const float4*)(pb2 + 36));

  f32x4 zero4 = {0.f, 0.f, 0.f, 0.f};
  f32x4 acc[2][4];
  #pragma unroll
  for (int rt = 0; rt < 2; ++rt)
    #pragma unroll
    for (int ct = 0; ct < 4; ++ct) acc[rt][ct] = zero4;

  #pragma unroll
  for (int kk = 0; kk < 6; ++kk) {
    int koff = kk * 32 + lk;
    #pragma unroll
    for (int ct = 0; ct < 4; ++ct) {
      s16x8 b = *(const s16x8*)&Wub[(ct * 16 + lr) * 192 + koff];
      acc[0][ct] = __builtin_amdgcn_mfma_f32_16x16x32_bf16(A0[kk], b, acc[0][ct], 0, 0, 0);
      acc[1][ct] = __builtin_amdgcn_mfma_f32_16x16x32_bf16(A1[kk], b, acc[1][ct], 0, 0, 0);
    }
  }

  if (PHASE == 0) {
    // per-feature sum / sumsq over this block's 128 edges
    float s1[4], s2[4];
    #pragma unroll
    for (int ct = 0; ct < 4; ++ct) {
      float bias = b_upd[ct * 16 + lr];
      float a1s = 0.f, a2s = 0.f;
      #pragma unroll
      for (int rt = 0; rt < 2; ++rt)
        #pragma unroll
        for (int q = 0; q < 4; ++q) {
          float v = acc[rt][ct][q] + bias;
          a1s += v; a2s += v * v;
        }
      s1[ct] = a1s; s2[ct] = a2s;
    }
    #pragma unroll
    for (int ct = 0; ct < 4; ++ct) {
      s1[ct] += __shfl_xor(s1[ct], 16); s1[ct] += __shfl_xor(s1[ct], 32);
      s2[ct] += __shfl_xor(s2[ct], 16); s2[ct] += __shfl_xor(s2[ct], 32);
    }
    if (ln < 16) {
      #pragma unroll
      for (int ct = 0; ct < 4; ++ct) {
        red[wv][ct * 16 + ln] = s1[ct];
        red[wv][64 + ct * 16 + ln] = s2[ct];
      }
    }
    __syncthreads();
    if (tid < 128) {
      float t = red[0][tid] + red[1][tid] + red[2][tid] + red[3][tid];
      atomicAdd(&ws[tid], t);   // tid<64 -> sum, 64..128 -> sumsq
    }
  } else {
    // e2 = e + silu(bn(e_lin))
    #pragma unroll
    for (int ct = 0; ct < 4; ++ct) {
      int col = ct * 16 + lr;
      float scale = ws[128 + col], shift = ws[192 + col], bias = b_upd[col];
      #pragma unroll
      for (int rt = 0; rt < 2; ++rt) {
        #pragma unroll
        for (int q = 0; q < 4; ++q) {
          int row = wv * 32 + rt * 16 + lq * 4 + q;
          size_t idx = (size_t)(m0 + row) * 64 + col;
          float x = acc[rt][ct][q] + bias;
          float bnv = x * scale + shift;
          float sl = bnv / (1.f + __expf(-bnv));
          out_e[idx] = e[idx] + sl;
        }
      }
    }
  }
}

// ---------------- finalize BN stats -> scale/shift ----------------
__global__ void k_fin(float* __restrict__ ws, const float* __restrict__ gamma,
                      const float* __restrict__ beta, float rcount, int off) {
  int d = threadIdx.x;
  float mean = ws[off + d] * rcount;
  float var = ws[off + 64 + d] * rcount - mean * mean;
  float inv = rsqrtf(var + EPS_BN);
  float a = inv * gamma[d];
  ws[off + 128 + d] = a;
  ws[off + 192 + d] = beta[d] - mean * a;
}

// ---------------- node stats: h2p = hgs + flag*hgd, accumulate sum/sumsq ----
__global__ __launch_bounds__(256, 2) void k_node_stats(
    const float* __restrict__ h,
    const float* __restrict__ W_gd, const float* __restrict__ b_gd,
    const float* __restrict__ W_gs, const float* __restrict__ b_gs,
    float* __restrict__ ws, const unsigned int* __restrict__ flags)
{
  __shared__ float Hs[64 * 64];
  __shared__ float Wd[64 * 64];
  __shared__ float Wg[64 * 64];
  __shared__ float red[2][256];
  int tid = threadIdx.x;
  int n0 = blockIdx.x * 64;
  for (int i = tid; i < 1024; i += 256) {
    int r = i >> 4, k4 = i & 15;
    int sw = (k4 ^ (r & 15)) << 2;
    *(float4*)&Wd[r * 64 + sw] = *(const float4*)&W_gd[(size_t)r * 64 + k4 * 4];
    *(float4*)&Wg[r * 64 + sw] = *(const float4*)&W_gs[(size_t)r * 64 + k4 * 4];
    int n = n0 + r;
    float4 hv = {0.f, 0.f, 0.f, 0.f};
    if (n < N_NODES) hv = *(const float4*)&h[(size_t)n * 64 + k4 * 4];
    *(float4*)&Hs[r * 64 + k4 * 4] = hv;
  }
  __syncthreads();
  int d = tid & 63, g = tid >> 6;
  float bd = b_gd[d], bs = b_gs[d];
  float s1 = 0.f, s2 = 0.f;
  #pragma unroll
  for (int i = 0; i < 16; ++i) {
    int nl = g + 4 * i;
    int n = n0 + nl;
    if (n < N_NODES) {
      float accd = 0.f, accs = 0.f;
      #pragma unroll
      for (int k4 = 0; k4 < 16; ++k4) {
        float4 hv = *(const float4*)&Hs[nl * 64 + k4 * 4];
        float4 w1 = *(const float4*)&Wd[d * 64 + ((k4 ^ (d & 15)) << 2)];
        float4 w2 = *(const float4*)&Wg[d * 64 + ((k4 ^ (d & 15)) << 2)];
        accd += hv.x * w1.x + hv.y * w1.y + hv.z * w1.z + hv.w * w1.w;
        accs += hv.x * w2.x + hv.y * w2.y + hv.z * w2.z + hv.w * w2.w;
      }
      unsigned int fl = (flags[n >> 5] >> (n & 31)) & 1u;
      float v = accs + bs + (fl ? (accd + bd) : 0.f);
      s1 += v; s2 += v * v;
    }
  }
  red[0][tid] = s1; red[1][tid] = s2;
  __syncthreads();
  if (tid < 64) {
    float t1 = red[0][tid] + red[0][tid + 64] + red[0][tid + 128] + red[0][tid + 192];
    float t2 = red[1][tid] + red[1][tid + 64] + red[1][tid + 128] + red[1][tid + 192];
    atomicAdd(&ws[256 + tid], t1);
    atomicAdd(&ws[320 + tid], t2);
  }
}

// ---------------- node output: h2 = (silu(bn(h2p)) + h) @ W_out.T + b_out ----
__global__ __launch_bounds__(256, 2) void k_node_out(
    const float* __restrict__ h,
    const float* __restrict__ W_gd, const float* __restrict__ b_gd,
    const float* __restrict__ W_gs, const float* __restrict__ b_gs,
    const float* __restrict__ W_out, const float* __restrict__ b_out,
    const float* __restrict__ ws, const unsigned int* __restrict__ flags,
    float* __restrict__ out_h)
{
  __shared__ float Hs[64 * 64];
  __shared__ float W1[64 * 64];
  __shared__ float W2[64 * 64];
  int tid = threadIdx.x;
  int n0 = blockIdx.x * 64;
  for (int i = tid; i < 1024; i += 256) {
    int r = i >> 4, k4 = i & 15;
    int sw = (k4 ^ (r & 15)) << 2;
    *(float4*)&W1[r * 64 + sw] = *(const float4*)&W_gd[(size_t)r * 64 + k4 * 4];
    *(float4*)&W2[r * 64 + sw] = *(const float4*)&W_gs[(size_t)r * 64 + k4 * 4];
    int n = n0 + r;
    float4 hv = {0.f, 0.f, 0.f, 0.f};
    if (n < N_NODES) hv = *(const float4*)&h[(size_t)n * 64 + k4 * 4];
    *(float4*)&Hs[r * 64 + k4 * 4] = hv;
  }
  __syncthreads();
  int d = tid & 63, g = tid >> 6;
  float a_n = ws[384 + d], b_n = ws[448 + d];
  float bd = b_gd[d], bs = b_gs[d];
  float tv[16];
  #pragma unroll
  for (int i = 0; i < 16; ++i) {
    int nl = g + 4 * i;
    int n = n0 + nl;
    if (n < N_NODES) {
      float accd = 0.f, accs = 0.f;
      #pragma unroll
      for (int k4 = 0; k4 < 16; ++k4) {
        float4 hv = *(const float4*)&Hs[nl * 64 + k4 * 4];
        float4 w1 = *(const float4*)&W1[d * 64 + ((k4 ^ (d & 15)) << 2)];
        float4 w2 = *(const float4*)&W2[d * 64 + ((k4 ^ (d & 15)) << 2)];
        accd += hv.x * w1.x + hv.y * w1.y + hv.z * w1.z + hv.w * w1.w;
        accs += hv.x * w2.x + hv.y * w2.y + hv.z * w2.z + hv.w * w2.w;
      }
      unsigned int fl = (flags[n >> 5] >> (n & 31)) & 1u;
      float v = accs + bs + (fl ? (accd + bd) : 0.f);
      float bnv = v * a_n + b_n;
      float sl = bnv / (1.f + __expf(-bnv));
      tv[i] = sl + Hs[nl * 64 + d];
    }
  }
  __syncthreads();   // all Hs/W1 reads complete
  for (int i = tid; i < 1024; i += 256) {
    int r = i >> 4, k4 = i & 15;
    *(float4*)&W1[r * 64 + ((k4 ^ (r & 15)) << 2)] = *(const float4*)&W_out[(size_t)r * 64 + k4 * 4];
  }
  #pragma unroll
  for (int i = 0; i < 16; ++i) {
    int nl = g + 4 * i;
    int n = n0 + nl;
    if (n < N_NODES) Hs[nl * 64 + d] = tv[i];
  }
  __syncthreads();
  float bo = b_out[d];
  #pragma unroll
  for (int i = 0; i < 16; ++i) {
    int nl = g + 4 * i;
    int n = n0 + nl;
    if (n < N_NODES) {
      float acc = 0.f;
      #pragma unroll
      for (int k4 = 0; k4 < 16; ++k4) {
        float4 t4 = *(const float4*)&Hs[nl * 64 + k4 * 4];
        float4 w4 = *(const float4*)&W1[d * 64 + ((k4 ^ (d & 15)) << 2)];
        acc += t4.x * w4.x + t4.y * w4.y + t4.z * w4.z + t4.w * w4.w;
      }
      out_h[(size_t)n * 64 + d] = acc + bo;
    }
  }
}

extern "C" void kernel_launch(void* const* d_in, const int* in_sizes, int n_in,
                              void* d_out, int out_size, void* d_ws, size_t ws_size,
                              hipStream_t stream) {
  const float* h     = (const float*)d_in[0];
  const float* e     = (const float*)d_in[1];
  const int*   src   = (const int*)d_in[2];
  const int*   dst   = (const int*)d_in[3];
  const float* W_upd = (const float*)d_in[4];
  const float* b_upd = (const float*)d_in[5];
  const float* g_un  = (const float*)d_in[6];
  const float* be_un = (const float*)d_in[7];
  // d_in[8], d_in[9]: W_act, b_act -- dead (softmax weights sum to 1 per dst)
  const float* W_gd  = (const float*)d_in[10];
  const float* b_gd  = (const float*)d_in[11];
  const float* W_gs  = (const float*)d_in[12];
  const float* b_gs  = (const float*)d_in[13];
  const float* g_gn  = (const float*)d_in[14];
  const float* be_gn = (const float*)d_in[15];
  const float* W_out = (const float*)d_in[16];
  const float* b_out = (const float*)d_in[17];

  float* outH = (float*)d_out;
  float* outE = outH + (size_t)N_NODES * 64;
  float* ws = (float*)d_ws;
  unsigned int* wsu = (unsigned int*)d_ws;
  unsigned int* flags = wsu + 512;
  const short* Wub = (const short*)(wsu + 2080);

  k_init<<<33, 256, 0, stream>>>(wsu, W_upd);
  k_edge<0><<<N_EDGES / 128, 256, 0, stream>>>(h, e, src, dst, Wub, b_upd, ws, flags, nullptr);
  k_fin<<<1, 64, 0, stream>>>(ws, g_un, be_un, 1.f / (float)N_EDGES, 0);
  k_edge<1><<<N_EDGES / 128, 256, 0, stream>>>(h, e, src, dst, Wub, b_upd, ws, flags, outE);
  k_node_stats<<<(N_NODES + 63) / 64, 256, 0, stream>>>(h, W_gd, b_gd, W_gs, b_gs, ws, flags);
  k_fin<<<1, 64, 0, stream>>>(ws, g_gn, be_gn, 1.f / (float)N_NODES, 256);
  k_node_out<<<(N_NODES + 63) / 64, 256, 0, stream>>>(h, W_gd, b_gd, W_gs, b_gs, W_out, b_out, ws, flags, outH);
}

// Round 4
// 368.872 us; speedup vs baseline: 1.5052x; 1.4127x over previous
//
#include <hip/hip_runtime.h>

#define N_NODES 50000
#define N_EDGES 800000
#define EPS_BN 1e-5f

// ws layout (32-bit words):
//  [0..64) sum_e [64..128) sumsq_e [128..192) scale_e [192..256) shift_e
//  [256..320) sum_n [320..384) sumsq_n [384..448) scale_n [448..512) shift_n
//  [512..6656)   W_upd bf16 (64x192)
//  [6656..8704)  W_gd bf16 (64x64)
//  [8704..10752) W_gs bf16 (64x64)
//  [10752..12800) W_out bf16 (64x64)
//  [12800..25300) per-node has-incoming-edge flag bytes (50000 B)

typedef __attribute__((ext_vector_type(8))) short s16x8;
typedef __attribute__((ext_vector_type(4))) float f32x4;

__device__ __forceinline__ unsigned short f2bf(float f) {
  unsigned int u = __float_as_uint(f);
  u += 0x7FFFu + ((u >> 16) & 1u);
  return (unsigned short)(u >> 16);
}
__device__ __forceinline__ unsigned int pack2(float lo, float hi) {
  return (unsigned int)f2bf(lo) | ((unsigned int)f2bf(hi) << 16);
}
__device__ __forceinline__ s16x8 cvt8(float4 a, float4 b) {
  union { s16x8 v; unsigned int u[4]; } r;
  r.u[0] = pack2(a.x, a.y); r.u[1] = pack2(a.z, a.w);
  r.u[2] = pack2(b.x, b.y); r.u[3] = pack2(b.z, b.w);
  return r.v;
}
__device__ __forceinline__ float siluf(float x) { return x / (1.f + __expf(-x)); }

// ---------------- K0: zero stats+flags, convert weights -> bf16 ----------------
__global__ void k_init(unsigned int* __restrict__ wsu,
                       const float* __restrict__ W_upd, const float* __restrict__ W_gd,
                       const float* __restrict__ W_gs, const float* __restrict__ W_out) {
  int i = blockIdx.x * 256 + threadIdx.x;
  if (i < 512) wsu[i] = 0u;
  if (i < 12500) wsu[12800 + i] = 0u;
  if (i < 6144) {
    float2 w2 = *(const float2*)&W_upd[(size_t)i * 2];
    wsu[512 + i] = pack2(w2.x, w2.y);
  }
  if (i < 2048) {
    float2 a = *(const float2*)&W_gd[(size_t)i * 2];
    float2 b = *(const float2*)&W_gs[(size_t)i * 2];
    float2 c = *(const float2*)&W_out[(size_t)i * 2];
    wsu[6656 + i] = pack2(a.x, a.y);
    wsu[8704 + i] = pack2(b.x, b.y);
    wsu[10752 + i] = pack2(c.x, c.y);
  }
}

// ---------------- flags: byte-store (idempotent, no atomics) ----------------
__global__ void k_flags(const int* __restrict__ dst, unsigned char* __restrict__ flb) {
  int i = blockIdx.x * 256 + threadIdx.x;
  if (i < N_EDGES) flb[dst[i]] = 1;
}

// ---------------- edge kernels: PHASE 0 = stats, PHASE 1 = output ----------------
// B (W_upd, 24KB bf16) staged in XOR-swizzled LDS: removes 24 global VMEM
// instrs/lane from the MFMA loop (TA-bound fix). A-fragments global->reg.
template<int PHASE>
__global__ __launch_bounds__(256, 4) void k_edge(
    const float* __restrict__ h, const float* __restrict__ e,
    const int* __restrict__ src, const int* __restrict__ dst,
    const unsigned int* __restrict__ wsu, const float* __restrict__ b_upd,
    float* __restrict__ ws, float* __restrict__ out_e)
{
  __shared__ short Bls[64 * 256];   // 64 rows x 512B (32 slots of 16B), XOR swizzled
  __shared__ float red[4][128];

  int tid = threadIdx.x;
  int ln = tid & 63, wv = tid >> 6;
  int lr = ln & 15, lq = ln >> 4, lk = lq * 8;
  int m0 = blockIdx.x * 128;
  int r0 = wv * 32 + lr, r1 = r0 + 16;
  int mA = m0 + r0, mB = m0 + r1;

  int s0 = src[mA], d0 = dst[mA];
  int s1i = src[mB], d1 = dst[mB];

  // B staging loads (independent of index chain)
  uint4 bst[6];
  const uint4* Wsrc = (const uint4*)(wsu + 512);
  #pragma unroll
  for (int j = 0; j < 6; ++j) bst[j] = Wsrc[tid + j * 256];

  const float* pa0 = h + (size_t)s0 * 64 + lk;
  const float* pa1 = h + (size_t)d0 * 64 + lk;
  const float* pa2 = e + (size_t)mA * 64 + lk;
  const float* pb0 = h + (size_t)s1i * 64 + lk;
  const float* pb1 = h + (size_t)d1 * 64 + lk;
  const float* pb2 = e + (size_t)mB * 64 + lk;

  s16x8 A0[6], A1[6];
  A0[0] = cvt8(*(const float4*)(pa0),      *(const float4*)(pa0 + 4));
  A0[1] = cvt8(*(const float4*)(pa0 + 32), *(const float4*)(pa0 + 36));
  A0[2] = cvt8(*(const float4*)(pa1),      *(const float4*)(pa1 + 4));
  A0[3] = cvt8(*(const float4*)(pa1 + 32), *(const float4*)(pa1 + 36));
  A0[4] = cvt8(*(const float4*)(pa2),      *(const float4*)(pa2 + 4));
  A0[5] = cvt8(*(const float4*)(pa2 + 32), *(const float4*)(pa2 + 36));
  A1[0] = cvt8(*(const float4*)(pb0),      *(const float4*)(pb0 + 4));
  A1[1] = cvt8(*(const float4*)(pb0 + 32), *(const float4*)(pb0 + 36));
  A1[2] = cvt8(*(const float4*)(pb1),      *(const float4*)(pb1 + 4));
  A1[3] = cvt8(*(const float4*)(pb1 + 32), *(const float4*)(pb1 + 36));
  A1[4] = cvt8(*(const float4*)(pb2),      *(const float4*)(pb2 + 4));
  A1[5] = cvt8(*(const float4*)(pb2 + 32), *(const float4*)(pb2 + 36));

  // write B to LDS (swizzled): chunk c -> row=c/24, i=c%24, slot = i^(row&7)
  #pragma unroll
  for (int j = 0; j < 6; ++j) {
    int c = tid + j * 256;
    int row = c / 24;
    int i = c - row * 24;
    ((uint4*)Bls)[row * 32 + (i ^ (row & 7))] = bst[j];
  }
  __syncthreads();

  f32x4 zero4 = {0.f, 0.f, 0.f, 0.f};
  f32x4 acc[2][4];
  #pragma unroll
  for (int rt = 0; rt < 2; ++rt)
    #pragma unroll
    for (int ct = 0; ct < 4; ++ct) acc[rt][ct] = zero4;

  #pragma unroll
  for (int ct = 0; ct < 4; ++ct) {
    int row = ct * 16 + lr, r7 = row & 7;
    #pragma unroll
    for (int kk = 0; kk < 6; ++kk) {
      s16x8 b = *(const s16x8*)&Bls[row * 256 + (((kk * 4 + lq) ^ r7) << 3)];
      acc[0][ct] = __builtin_amdgcn_mfma_f32_16x16x32_bf16(A0[kk], b, acc[0][ct], 0, 0, 0);
      acc[1][ct] = __builtin_amdgcn_mfma_f32_16x16x32_bf16(A1[kk], b, acc[1][ct], 0, 0, 0);
    }
  }

  if (PHASE == 0) {
    float s1[4], s2[4];
    #pragma unroll
    for (int ct = 0; ct < 4; ++ct) {
      float bias = b_upd[ct * 16 + lr];
      float a1s = 0.f, a2s = 0.f;
      #pragma unroll
      for (int rt = 0; rt < 2; ++rt)
        #pragma unroll
        for (int q = 0; q < 4; ++q) {
          float v = acc[rt][ct][q] + bias;
          a1s += v; a2s += v * v;
        }
      s1[ct] = a1s; s2[ct] = a2s;
    }
    #pragma unroll
    for (int ct = 0; ct < 4; ++ct) {
      s1[ct] += __shfl_xor(s1[ct], 16); s1[ct] += __shfl_xor(s1[ct], 32);
      s2[ct] += __shfl_xor(s2[ct], 16); s2[ct] += __shfl_xor(s2[ct], 32);
    }
    if (ln < 16) {
      #pragma unroll
      for (int ct = 0; ct < 4; ++ct) {
        red[wv][ct * 16 + ln] = s1[ct];
        red[wv][64 + ct * 16 + ln] = s2[ct];
      }
    }
    __syncthreads();
    if (tid < 128) {
      float t = red[0][tid] + red[1][tid] + red[2][tid] + red[3][tid];
      atomicAdd(&ws[tid], t);
    }
  } else {
    #pragma unroll
    for (int ct = 0; ct < 4; ++ct) {
      int col = ct * 16 + lr;
      float scale = ws[128 + col], shift = ws[192 + col], bias = b_upd[col];
      #pragma unroll
      for (int rt = 0; rt < 2; ++rt) {
        #pragma unroll
        for (int q = 0; q < 4; ++q) {
          int row = wv * 32 + rt * 16 + lq * 4 + q;
          size_t idx = (size_t)(m0 + row) * 64 + col;
          float x = acc[rt][ct][q] + bias;
          out_e[idx] = e[idx] + siluf(x * scale + shift);
        }
      }
    }
  }
}

// ---------------- finalize BN stats -> scale/shift ----------------
__global__ void k_fin(float* __restrict__ ws, const float* __restrict__ gamma,
                      const float* __restrict__ beta, float rcount, int off) {
  int d = threadIdx.x;
  float mean = ws[off + d] * rcount;
  float var = ws[off + 64 + d] * rcount - mean * mean;
  float inv = rsqrtf(var + EPS_BN);
  float a = inv * gamma[d];
  ws[off + 128 + d] = a;
  ws[off + 192 + d] = beta[d] - mean * a;
}

// ---------------- node stats (MFMA): v = hgs + fl*hgd, accumulate sum/sumsq ----
__global__ __launch_bounds__(256, 4) void k_nstat(
    const float* __restrict__ h, const unsigned int* __restrict__ wsu,
    const unsigned char* __restrict__ flb,
    const float* __restrict__ b_gd, const float* __restrict__ b_gs,
    float* __restrict__ ws)
{
  __shared__ short Bgd[64 * 64], Bgs[64 * 64];   // 8KB each, 128B rows, swizzled
  __shared__ float red[4][128];
  int tid = threadIdx.x;
  int ln = tid & 63, wv = tid >> 6;
  int lr = ln & 15, lq = ln >> 4, lk = lq * 8;
  int n0 = blockIdx.x * 128;

  const uint4* Sgd = (const uint4*)(wsu + 6656);
  const uint4* Sgs = (const uint4*)(wsu + 8704);
  #pragma unroll
  for (int j = 0; j < 2; ++j) {
    int c = tid + j * 256;
    int row = c >> 3, i = c & 7, sl = row * 8 + (i ^ (row & 7));
    ((uint4*)Bgd)[sl] = Sgd[c];
    ((uint4*)Bgs)[sl] = Sgs[c];
  }

  int r0 = wv * 32 + lr, r1 = r0 + 16;
  int nA = min(n0 + r0, N_NODES - 1), nB = min(n0 + r1, N_NODES - 1);
  const float* pa = h + (size_t)nA * 64 + lk;
  const float* pb = h + (size_t)nB * 64 + lk;
  s16x8 A0[2], A1[2];
  A0[0] = cvt8(*(const float4*)(pa),      *(const float4*)(pa + 4));
  A0[1] = cvt8(*(const float4*)(pa + 32), *(const float4*)(pa + 36));
  A1[0] = cvt8(*(const float4*)(pb),      *(const float4*)(pb + 4));
  A1[1] = cvt8(*(const float4*)(pb + 32), *(const float4*)(pb + 36));
  __syncthreads();

  f32x4 zero4 = {0.f, 0.f, 0.f, 0.f};
  f32x4 accd[2][4], accs[2][4];
  #pragma unroll
  for (int rt = 0; rt < 2; ++rt)
    #pragma unroll
    for (int ct = 0; ct < 4; ++ct) { accd[rt][ct] = zero4; accs[rt][ct] = zero4; }

  #pragma unroll
  for (int ct = 0; ct < 4; ++ct) {
    int row = ct * 16 + lr, r7 = row & 7;
    #pragma unroll
    for (int kk = 0; kk < 2; ++kk) {
      int sl = ((kk * 4 + lq) ^ r7) << 3;
      s16x8 bd = *(const s16x8*)&Bgd[row * 64 + sl];
      s16x8 bs = *(const s16x8*)&Bgs[row * 64 + sl];
      accd[0][ct] = __builtin_amdgcn_mfma_f32_16x16x32_bf16(A0[kk], bd, accd[0][ct], 0, 0, 0);
      accd[1][ct] = __builtin_amdgcn_mfma_f32_16x16x32_bf16(A1[kk], bd, accd[1][ct], 0, 0, 0);
      accs[0][ct] = __builtin_amdgcn_mfma_f32_16x16x32_bf16(A0[kk], bs, accs[0][ct], 0, 0, 0);
      accs[1][ct] = __builtin_amdgcn_mfma_f32_16x16x32_bf16(A1[kk], bs, accs[1][ct], 0, 0, 0);
    }
  }

  float s1[4], s2[4];
  #pragma unroll
  for (int ct = 0; ct < 4; ++ct) {
    int col = ct * 16 + lr;
    float bd = b_gd[col], bs = b_gs[col];
    float a1s = 0.f, a2s = 0.f;
    #pragma unroll
    for (int rt = 0; rt < 2; ++rt)
      #pragma unroll
      for (int q = 0; q < 4; ++q) {
        int row = wv * 32 + rt * 16 + lq * 4 + q;
        int n = n0 + row;
        if (n < N_NODES) {
          float fl = (float)flb[n];
          float v = accs[rt][ct][q] + bs + fl * (accd[rt][ct][q] + bd);
          a1s += v; a2s += v * v;
        }
      }
    s1[ct] = a1s; s2[ct] = a2s;
  }
  #pragma unroll
  for (int ct = 0; ct < 4; ++ct) {
    s1[ct] += __shfl_xor(s1[ct], 16); s1[ct] += __shfl_xor(s1[ct], 32);
    s2[ct] += __shfl_xor(s2[ct], 16); s2[ct] += __shfl_xor(s2[ct], 32);
  }
  if (ln < 16) {
    #pragma unroll
    for (int ct = 0; ct < 4; ++ct) {
      red[wv][ct * 16 + ln] = s1[ct];
      red[wv][64 + ct * 16 + ln] = s2[ct];
    }
  }
  __syncthreads();
  if (tid < 128) {
    float t = red[0][tid] + red[1][tid] + red[2][tid] + red[3][tid];
    atomicAdd(&ws[256 + tid], t);
  }
}

// ---------------- node output (MFMA x2): t = silu(bn(v)) + h; out = t@W_out.T + b ----
__global__ __launch_bounds__(256, 4) void k_nout(
    const float* __restrict__ h, const unsigned int* __restrict__ wsu,
    const unsigned char* __restrict__ flb,
    const float* __restrict__ b_gd, const float* __restrict__ b_gs,
    const float* __restrict__ b_out, const float* __restrict__ ws,
    float* __restrict__ out_h)
{
  __shared__ short R1[128 * 64];   // first Bgd|Bgs (8KB+8KB), then t-tile (16KB)
  __shared__ short R2[64 * 64];    // W_out (8KB)
  int tid = threadIdx.x;
  int ln = tid & 63, wv = tid >> 6;
  int lr = ln & 15, lq = ln >> 4, lk = lq * 8;
  int n0 = blockIdx.x * 128;

  const uint4* Sgd = (const uint4*)(wsu + 6656);
  const uint4* Sgs = (const uint4*)(wsu + 8704);
  const uint4* Sot = (const uint4*)(wsu + 10752);
  short* Bgd = R1;
  short* Bgs = R1 + 4096;
  #pragma unroll
  for (int j = 0; j < 2; ++j) {
    int c = tid + j * 256;
    int row = c >> 3, i = c & 7, sl = row * 8 + (i ^ (row & 7));
    ((uint4*)Bgd)[sl] = Sgd[c];
    ((uint4*)Bgs)[sl] = Sgs[c];
    ((uint4*)R2)[sl] = Sot[c];
  }

  int r0 = wv * 32 + lr, r1 = r0 + 16;
  int nA = min(n0 + r0, N_NODES - 1), nB = min(n0 + r1, N_NODES - 1);
  const float* pa = h + (size_t)nA * 64 + lk;
  const float* pb = h + (size_t)nB * 64 + lk;
  s16x8 A0[2], A1[2];
  A0[0] = cvt8(*(const float4*)(pa),      *(const float4*)(pa + 4));
  A0[1] = cvt8(*(const float4*)(pa + 32), *(const float4*)(pa + 36));
  A1[0] = cvt8(*(const float4*)(pb),      *(const float4*)(pb + 4));
  A1[1] = cvt8(*(const float4*)(pb + 32), *(const float4*)(pb + 36));
  __syncthreads();

  f32x4 zero4 = {0.f, 0.f, 0.f, 0.f};
  f32x4 accd[2][4], accs[2][4];
  #pragma unroll
  for (int rt = 0; rt < 2; ++rt)
    #pragma unroll
    for (int ct = 0; ct < 4; ++ct) { accd[rt][ct] = zero4; accs[rt][ct] = zero4; }

  #pragma unroll
  for (int ct = 0; ct < 4; ++ct) {
    int row = ct * 16 + lr, r7 = row & 7;
    #pragma unroll
    for (int kk = 0; kk < 2; ++kk) {
      int sl = ((kk * 4 + lq) ^ r7) << 3;
      s16x8 bd = *(const s16x8*)&Bgd[row * 64 + sl];
      s16x8 bs = *(const s16x8*)&Bgs[row * 64 + sl];
      accd[0][ct] = __builtin_amdgcn_mfma_f32_16x16x32_bf16(A0[kk], bd, accd[0][ct], 0, 0, 0);
      accd[1][ct] = __builtin_amdgcn_mfma_f32_16x16x32_bf16(A1[kk], bd, accd[1][ct], 0, 0, 0);
      accs[0][ct] = __builtin_amdgcn_mfma_f32_16x16x32_bf16(A0[kk], bs, accs[0][ct], 0, 0, 0);
      accs[1][ct] = __builtin_amdgcn_mfma_f32_16x16x32_bf16(A1[kk], bs, accs[1][ct], 0, 0, 0);
    }
  }

  // t = silu(bn(v)) + h   (kept in regs across the LDS repurposing barrier)
  float tv[4][2][4];   // [ct][rt][q]  (r3 bug: was [2][4][4] -> OOB UB)
  #pragma unroll
  for (int ct = 0; ct < 4; ++ct) {
    int col = ct * 16 + lr;
    float a_n = ws[384 + col], b_n = ws[448 + col];
    float bd = b_gd[col], bs = b_gs[col];
    #pragma unroll
    for (int rt = 0; rt < 2; ++rt)
      #pragma unroll
      for (int q = 0; q < 4; ++q) {
        int row = wv * 32 + rt * 16 + lq * 4 + q;
        int n = min(n0 + row, N_NODES - 1);
        float fl = (float)flb[n];
        float v = accs[rt][ct][q] + bs + fl * (accd[rt][ct][q] + bd);
        tv[ct][rt][q] = siluf(v * a_n + b_n) + h[(size_t)n * 64 + col];
      }
  }
  __syncthreads();   // everyone done reading Bgd/Bgs
  // write t-tile (bf16, swizzled rows of 128B) into R1
  #pragma unroll
  for (int ct = 0; ct < 4; ++ct) {
    int col = ct * 16 + lr;
    #pragma unroll
    for (int rt = 0; rt < 2; ++rt)
      #pragma unroll
      for (int q = 0; q < 4; ++q) {
        int row = wv * 32 + rt * 16 + lq * 4 + q;
        R1[row * 64 + (((col >> 3) ^ (row & 7)) << 3) + (col & 7)] = (short)f2bf(tv[ct][rt][q]);
      }
  }
  __syncthreads();

  s16x8 T0[2], T1[2];
  #pragma unroll
  for (int kk = 0; kk < 2; ++kk) {
    T0[kk] = *(const s16x8*)&R1[r0 * 64 + (((kk * 4 + lq) ^ (r0 & 7)) << 3)];
    T1[kk] = *(const s16x8*)&R1[r1 * 64 + (((kk * 4 + lq) ^ (r1 & 7)) << 3)];
  }
  f32x4 ac2[2][4];
  #pragma unroll
  for (int rt = 0; rt < 2; ++rt)
    #pragma unroll
    for (int ct = 0; ct < 4; ++ct) ac2[rt][ct] = zero4;
  #pragma unroll
  for (int ct = 0; ct < 4; ++ct) {
    int row = ct * 16 + lr, r7 = row & 7;
    #pragma unroll
    for (int kk = 0; kk < 2; ++kk) {
      s16x8 b = *(const s16x8*)&R2[row * 64 + (((kk * 4 + lq) ^ r7) << 3)];
      ac2[0][ct] = __builtin_amdgcn_mfma_f32_16x16x32_bf16(T0[kk], b, ac2[0][ct], 0, 0, 0);
      ac2[1][ct] = __builtin_amdgcn_mfma_f32_16x16x32_bf16(T1[kk], b, ac2[1][ct], 0, 0, 0);
    }
  }
  #pragma unroll
  for (int ct = 0; ct < 4; ++ct) {
    int col = ct * 16 + lr;
    float bo = b_out[col];
    #pragma unroll
    for (int rt = 0; rt < 2; ++rt)
      #pragma unroll
      for (int q = 0; q < 4; ++q) {
        int row = wv * 32 + rt * 16 + lq * 4 + q;
        int n = n0 + row;
        if (n < N_NODES) out_h[(size_t)n * 64 + col] = ac2[rt][ct][q] + bo;
      }
  }
}

extern "C" void kernel_launch(void* const* d_in, const int* in_sizes, int n_in,
                              void* d_out, int out_size, void* d_ws, size_t ws_size,
                              hipStream_t stream) {
  const float* h     = (const float*)d_in[0];
  const float* e     = (const float*)d_in[1];
  const int*   src   = (const int*)d_in[2];
  const int*   dst   = (const int*)d_in[3];
  const float* W_upd = (const float*)d_in[4];
  const float* b_upd = (const float*)d_in[5];
  const float* g_un  = (const float*)d_in[6];
  const float* be_un = (const float*)d_in[7];
  // d_in[8], d_in[9]: W_act, b_act -- dead (softmax weights sum to 1 per dst)
  const float* W_gd  = (const float*)d_in[10];
  const float* b_gd  = (const float*)d_in[11];
  const float* W_gs  = (const float*)d_in[12];
  const float* b_gs  = (const float*)d_in[13];
  const float* g_gn  = (const float*)d_in[14];
  const float* be_gn = (const float*)d_in[15];
  const float* W_out = (const float*)d_in[16];
  const float* b_out = (const float*)d_in[17];

  float* outH = (float*)d_out;
  float* outE = outH + (size_t)N_NODES * 64;
  float* ws = (float*)d_ws;
  unsigned int* wsu = (unsigned int*)d_ws;
  unsigned char* flb = (unsigned char*)(wsu + 12800);

  k_init<<<49, 256, 0, stream>>>(wsu, W_upd, W_gd, W_gs, W_out);
  k_flags<<<(N_EDGES + 255) / 256, 256, 0, stream>>>(dst, flb);
  k_edge<0><<<N_EDGES / 128, 256, 0, stream>>>(h, e, src, dst, wsu, b_upd, ws, nullptr);
  k_fin<<<1, 64, 0, stream>>>(ws, g_un, be_un, 1.f / (float)N_EDGES, 0);
  k_edge<1><<<N_EDGES / 128, 256, 0, stream>>>(h, e, src, dst, wsu, b_upd, ws, outE);
  k_nstat<<<(N_NODES + 127) / 128, 256, 0, stream>>>(h, wsu, flb, b_gd, b_gs, ws);
  k_fin<<<1, 64, 0, stream>>>(ws, g_gn, be_gn, 1.f / (float)N_NODES, 256);
  k_nout<<<(N_NODES + 127) / 128, 256, 0, stream>>>(h, wsu, flb, b_gd, b_gs, b_out, ws, outH);
}